// Round 7
// baseline (291.826 us; speedup 1.0000x reference)
//
#include <hip/hip_runtime.h>
#include <math.h>

#define BB 8
#define SS 4096
#define DD 64
#define NT (SS / 64)
#define LOG2E 1.4426950408889634f

typedef float  f32x4 __attribute__((ext_vector_type(4)));
typedef short  s16x4 __attribute__((ext_vector_type(4)));
typedef short  s16x8 __attribute__((ext_vector_type(8)));
typedef unsigned char u8x16 __attribute__((ext_vector_type(16)));

__device__ __forceinline__ short f2bf(float f) {
  unsigned u = __builtin_bit_cast(unsigned, f);
  u += 0x7FFFu + ((u >> 16) & 1u);
  return (short)(u >> 16);
}

// packed f32x2 -> bf16x2 (RNE) via hardware cvt_pk (no builtin on gfx950)
__device__ __forceinline__ unsigned pk_bf16(float lo, float hi) {
  unsigned r;
  asm("v_cvt_pk_bf16_f32 %0, %1, %2" : "=v"(r) : "v"(lo), "v"(hi));
  return r;
}

// ---------------- kernel 1: L2-normalize q,k rows -> bf16 ----------------
// q additionally scaled by log2(e) so scores are in log2 domain (native v_exp).
__global__ __launch_bounds__(256) void k_norm(const float* __restrict__ q,
                                              const float* __restrict__ k,
                                              short* __restrict__ qn,
                                              short* __restrict__ kn) {
  const long BS = (long)BB * SS;
  long row = (long)blockIdx.x * 4 + (threadIdx.x >> 6);
  int lane = threadIdx.x & 63;
  const float* src;
  short* dst;
  float sc;
  if (row < BS) { src = q + row * DD; dst = qn + row * DD; sc = LOG2E; }
  else          { src = k + (row - BS) * DD; dst = kn + (row - BS) * DD; sc = 1.0f; }
  float x = src[lane];
  float ss = x * x;
#pragma unroll
  for (int m = 32; m >= 1; m >>= 1) ss += __shfl_xor(ss, m);
  float inv = sc / (sqrtf(ss) + 1e-10f);
  dst[lane] = f2bf(x * inv);
}

// ---------------- kernel 2: V -> VT[b][d][s] bf16 ----------------
__global__ __launch_bounds__(256) void k_vtrans(const float* __restrict__ v,
                                                short* __restrict__ vt) {
  __shared__ short tile[64][65];
  int b = blockIdx.y;
  int s0 = blockIdx.x * 64;
  const float* V = v + ((long)b * SS + s0) * DD;
  int t = threadIdx.x;
#pragma unroll
  for (int i = 0; i < 16; i++) {
    int flat = t + 256 * i;            // flat = sl*64 + d
    int sl = flat >> 6, d = flat & 63;
    tile[sl][d] = f2bf(V[flat]);
  }
  __syncthreads();
  short* VT = vt + (long)b * DD * SS + s0;
#pragma unroll
  for (int i = 0; i < 16; i++) {
    int flat = t + 256 * i;            // flat = d*64 + sl
    int d = flat >> 6, sl = flat & 63;
    VT[(long)d * SS + sl] = tile[sl][d];
  }
}

// ------- pass A: linear mask->bits (LDS + global) then exp row-sums -------
// Block = 64 q rows, full K sweep. Phase 0: stream the block's CONTIGUOUS
// 256 KB mask slice (64 coalesced 4-KB iters), pack to bits in LDS
// (XOR-swizzled u64 cols) and to global bits16 for pass B. Phase 1: r2's
// K-dbuf MFMA sweep with in-LDS mask bits and a no-mask fast path.
__global__ __launch_bounds__(256) void k_rowsum(const short* __restrict__ qn,
                                                const short* __restrict__ kn,
                                                const unsigned char* __restrict__ mask,
                                                unsigned short* __restrict__ bits16,
                                                float* __restrict__ accG) {
  __shared__ __align__(16) short Kt[2][4096];              // 16 KB
  __shared__ __align__(16) unsigned long long bitsL[64 * 64]; // 32 KB [row][colSwz]
  unsigned short* bitsLu16 = (unsigned short*)bitsL;

  int b = blockIdx.x & 7;
  int q0 = (blockIdx.x >> 3) << 6;
  int tid = threadIdx.x;
  int wid = tid >> 6, lane = tid & 63;
  int l15 = lane & 15, g = lane >> 4;
  int qr = q0 + (wid << 4);

  // ---- phase 0: mask streaming (linear) ----
  const unsigned char* Mb = mask + ((long)(b * SS) + q0) * SS;
  unsigned short* Bg = bits16 + ((long)(b * SS) + q0) * 256 + tid;
#pragma unroll 4
  for (int i = 0; i < 64; ++i) {
    u8x16 m = __builtin_nontemporal_load((const u8x16*)(Mb + (long)i * SS + tid * 16));
    unsigned r = 0;
#pragma unroll
    for (int j = 0; j < 16; ++j) r |= (m[j] ? 1u : 0u) << j;
    int cs = ((tid >> 2) ^ i) & 63;                 // swizzled u64 col
    bitsLu16[i * 256 + cs * 4 + (tid & 3)] = (unsigned short)r;
    __builtin_nontemporal_store((unsigned short)r, Bg + i * 256);
  }

  // ---- K prologue ----
  const short* Qr = qn + ((long)(b * SS) + qr + l15) * DD;
  s16x8 qf0 = *(const s16x8*)(Qr + 8 * g);
  s16x8 qf1 = *(const s16x8*)(Qr + 32 + 8 * g);

  const short* Kb = kn + (long)b * SS * DD;
  int sr = lane >> 3, sc = lane & 7;
  int r0 = (wid << 4) + sr, r1 = r0 + 8;
  const short* Ksrc0 = Kb + (long)r0 * DD + sc * 8;
  const short* Ksrc1 = Kb + (long)r1 * DD + sc * 8;
  int kd0 = r0 * DD + ((sc ^ sr) << 3);
  int kd1 = r1 * DD + ((sc ^ sr) << 3);
  int swk = l15 & 7;
  int brow = (wid << 4) + l15;                      // this lane's bitsL row

  s16x8 kst0 = *(const s16x8*)Ksrc0;
  s16x8 kst1 = *(const s16x8*)Ksrc1;
  *(s16x8*)&Kt[0][kd0] = kst0;
  *(s16x8*)&Kt[0][kd1] = kst1;
  __syncthreads();

  // ---- phase 1: sweep ----
  float acc = 0.f;
  int cur = 0;
  for (int t = 0; t < NT; ++t) {
    if (t + 1 < NT) {
      long koff = (long)(t + 1) * 64 * DD;
      kst0 = *(const s16x8*)(Ksrc0 + koff);
      kst1 = *(const s16x8*)(Ksrc1 + koff);
    }
    unsigned long long w64 = bitsL[brow * 64 + ((t ^ brow) & 63)];
    const short* Kc = &Kt[cur][0];
    if (__builtin_expect(__all(w64 == 0ull), 1)) {
#pragma unroll
      for (int tt = 0; tt < 4; ++tt) {
        const short* krow = Kc + ((tt << 4) + l15) * DD;
        s16x8 a0 = *(const s16x8*)(krow + ((g ^ swk) << 3));
        s16x8 a1 = *(const s16x8*)(krow + (((4 + g) ^ swk) << 3));
        f32x4 c = {0.f, 0.f, 0.f, 0.f};
        c = __builtin_amdgcn_mfma_f32_16x16x32_bf16(a0, qf0, c, 0, 0, 0);
        c = __builtin_amdgcn_mfma_f32_16x16x32_bf16(a1, qf1, c, 0, 0, 0);
#pragma unroll
        for (int r = 0; r < 4; ++r) acc += exp2f(c[r]);
      }
    } else {
#pragma unroll
      for (int tt = 0; tt < 4; ++tt) {
        const short* krow = Kc + ((tt << 4) + l15) * DD;
        s16x8 a0 = *(const s16x8*)(krow + ((g ^ swk) << 3));
        s16x8 a1 = *(const s16x8*)(krow + (((4 + g) ^ swk) << 3));
        f32x4 c = {0.f, 0.f, 0.f, 0.f};
        c = __builtin_amdgcn_mfma_f32_16x16x32_bf16(a0, qf0, c, 0, 0, 0);
        c = __builtin_amdgcn_mfma_f32_16x16x32_bf16(a1, qf1, c, 0, 0, 0);
#pragma unroll
        for (int r = 0; r < 4; ++r) {
          unsigned bit = (unsigned)(w64 >> ((tt << 4) + (g << 2) + r)) & 1u;
          acc += bit ? 0.f : exp2f(c[r]);
        }
      }
    }
    if (t + 1 < NT) {
      short* Kd = &Kt[cur ^ 1][0];
      *(s16x8*)(Kd + kd0) = kst0;
      *(s16x8*)(Kd + kd1) = kst1;
    }
    __syncthreads();
    cur ^= 1;
  }
  acc += __shfl_xor(acc, 16);
  acc += __shfl_xor(acc, 32);
  if (lane < 16) accG[(long)b * SS + qr + l15] = acc;
}

// ------- pass B: recompute scores, write normalized P, accumulate O -------
__global__ __launch_bounds__(256) void k_attn(const short* __restrict__ qn,
                                              const short* __restrict__ kn,
                                              const short* __restrict__ vt,
                                              const unsigned short* __restrict__ bits,
                                              const float* __restrict__ accG,
                                              float* __restrict__ O,
                                              float* __restrict__ P) {
  __shared__ __align__(16) short Kt[2][4096];
  __shared__ __align__(16) short Vt[2][4096];
  int b = blockIdx.x & 7;
  int q0 = (blockIdx.x >> 3) << 6;
  int wid = threadIdx.x >> 6, lane = threadIdx.x & 63;
  int l15 = lane & 15, g = lane >> 4;
  int qr = q0 + (wid << 4);

  const short* Qr = qn + ((long)(b * SS) + qr + l15) * DD;
  s16x8 qf0 = *(const s16x8*)(Qr + 8 * g);
  s16x8 qf1 = *(const s16x8*)(Qr + 32 + 8 * g);

  const short* Kb = kn + (long)b * SS * DD;
  const short* Vb = vt + (long)b * DD * SS;
  long rowid = (long)b * SS + qr + l15;
  const unsigned long long* B64 = (const unsigned long long*)bits + rowid * (SS / 64);
  float linv2 = -__log2f(accG[rowid]);
  float* Prow = P + rowid * SS;

  int sr = lane >> 3, sc = lane & 7;
  int r0 = (wid << 4) + sr, r1 = r0 + 8;
  const short* Ksrc0 = Kb + (long)r0 * DD + sc * 8;
  const short* Ksrc1 = Kb + (long)r1 * DD + sc * 8;
  const short* Vsrc0 = Vb + (long)r0 * SS + sc * 8;
  const short* Vsrc1 = Vb + (long)r1 * SS + sc * 8;
  int sd0 = r0 * DD + ((sc ^ sr) << 3);
  int sd1 = r1 * DD + ((sc ^ sr) << 3);
  int swk = l15 & 7;

  s16x8 kst0 = *(const s16x8*)Ksrc0;
  s16x8 kst1 = *(const s16x8*)Ksrc1;
  s16x8 vst0 = *(const s16x8*)Vsrc0;
  s16x8 vst1 = *(const s16x8*)Vsrc1;
  *(s16x8*)&Kt[0][sd0] = kst0;
  *(s16x8*)&Kt[0][sd1] = kst1;
  *(s16x8*)&Vt[0][sd0] = vst0;
  *(s16x8*)&Vt[0][sd1] = vst1;
  __syncthreads();

  f32x4 o0 = {0, 0, 0, 0}, o1 = {0, 0, 0, 0}, o2 = {0, 0, 0, 0}, o3 = {0, 0, 0, 0};
  int cur = 0;
  for (int t = 0; t < NT; ++t) {
    if (t + 1 < NT) {
      long koff = (long)(t + 1) * 64 * DD;
      kst0 = *(const s16x8*)(Ksrc0 + koff);
      kst1 = *(const s16x8*)(Ksrc1 + koff);
      vst0 = *(const s16x8*)(Vsrc0 + (t + 1) * 64);
      vst1 = *(const s16x8*)(Vsrc1 + (t + 1) * 64);
    }
    unsigned long long w64 = B64[t];
    const short* Kc = &Kt[cur][0];
    const short* Vc = &Vt[cur][0];

    f32x4 p[4];
    if (__builtin_expect(__all(w64 == 0ull), 1)) {
#pragma unroll
      for (int tt = 0; tt < 4; ++tt) {
        const short* krow = Kc + ((tt << 4) + l15) * DD;
        s16x8 a0 = *(const s16x8*)(krow + ((g ^ swk) << 3));
        s16x8 a1 = *(const s16x8*)(krow + (((4 + g) ^ swk) << 3));
        f32x4 c = {0.f, 0.f, 0.f, 0.f};
        c = __builtin_amdgcn_mfma_f32_16x16x32_bf16(a0, qf0, c, 0, 0, 0);
        c = __builtin_amdgcn_mfma_f32_16x16x32_bf16(a1, qf1, c, 0, 0, 0);
#pragma unroll
        for (int r = 0; r < 4; ++r) p[tt][r] = exp2f(c[r] + linv2);
        __builtin_nontemporal_store(p[tt],
            (f32x4*)(Prow + (t << 6) + (tt << 4) + (g << 2)));
      }
    } else {
#pragma unroll
      for (int tt = 0; tt < 4; ++tt) {
        const short* krow = Kc + ((tt << 4) + l15) * DD;
        s16x8 a0 = *(const s16x8*)(krow + ((g ^ swk) << 3));
        s16x8 a1 = *(const s16x8*)(krow + (((4 + g) ^ swk) << 3));
        f32x4 c = {0.f, 0.f, 0.f, 0.f};
        c = __builtin_amdgcn_mfma_f32_16x16x32_bf16(a0, qf0, c, 0, 0, 0);
        c = __builtin_amdgcn_mfma_f32_16x16x32_bf16(a1, qf1, c, 0, 0, 0);
#pragma unroll
        for (int r = 0; r < 4; ++r) {
          unsigned bit = (unsigned)(w64 >> ((tt << 4) + (g << 2) + r)) & 1u;
          p[tt][r] = bit ? 0.f : exp2f(c[r] + linv2);
        }
        __builtin_nontemporal_store(p[tt],
            (f32x4*)(Prow + (t << 6) + (tt << 4) + (g << 2)));
      }
    }

    // pack P -> bf16 A-operands via v_cvt_pk_bf16_f32 (RNE)
    union { s16x8 v; unsigned u[4]; } pa0, pa1;
    pa0.u[0] = pk_bf16(p[0][0], p[0][1]);
    pa0.u[1] = pk_bf16(p[0][2], p[0][3]);
    pa0.u[2] = pk_bf16(p[1][0], p[1][1]);
    pa0.u[3] = pk_bf16(p[1][2], p[1][3]);
    pa1.u[0] = pk_bf16(p[2][0], p[2][1]);
    pa1.u[1] = pk_bf16(p[2][2], p[2][3]);
    pa1.u[2] = pk_bf16(p[3][0], p[3][1]);
    pa1.u[3] = pk_bf16(p[3][2], p[3][3]);

#pragma unroll
    for (int n = 0; n < 4; ++n) {
      const short* vrow = Vc + ((n << 4) + l15) * DD;
      int g2 = g >> 1, hh = (g & 1) << 2;
      s16x4 lo0 = *(const s16x4*)(vrow + (((g2    ) ^ swk) << 3) + hh);
      s16x4 hi0 = *(const s16x4*)(vrow + (((g2 + 2) ^ swk) << 3) + hh);
      s16x4 lo1 = *(const s16x4*)(vrow + (((g2 + 4) ^ swk) << 3) + hh);
      s16x4 hi1 = *(const s16x4*)(vrow + (((g2 + 6) ^ swk) << 3) + hh);
      s16x8 vf0 = __builtin_shufflevector(lo0, hi0, 0, 1, 2, 3, 4, 5, 6, 7);
      s16x8 vf1 = __builtin_shufflevector(lo1, hi1, 0, 1, 2, 3, 4, 5, 6, 7);
      f32x4* on = (n == 0) ? &o0 : (n == 1) ? &o1 : (n == 2) ? &o2 : &o3;
      *on = __builtin_amdgcn_mfma_f32_16x16x32_bf16(pa0.v, vf0, *on, 0, 0, 0);
      *on = __builtin_amdgcn_mfma_f32_16x16x32_bf16(pa1.v, vf1, *on, 0, 0, 0);
    }

    if (t + 1 < NT) {
      short* Kd = &Kt[cur ^ 1][0];
      short* Vd = &Vt[cur ^ 1][0];
      *(s16x8*)(Kd + sd0) = kst0;
      *(s16x8*)(Kd + sd1) = kst1;
      *(s16x8*)(Vd + sd0) = vst0;
      *(s16x8*)(Vd + sd1) = vst1;
    }
    __syncthreads();
    cur ^= 1;
  }

  float* Ob = O + ((long)(b * SS) + qr) * DD;
#pragma unroll
  for (int r = 0; r < 4; ++r) {
    int row = (g << 2) + r;
    Ob[row * DD +  0 + l15] = o0[r];
    Ob[row * DD + 16 + l15] = o1[r];
    Ob[row * DD + 32 + l15] = o2[r];
    Ob[row * DD + 48 + l15] = o3[r];
  }
}

extern "C" void kernel_launch(void* const* d_in, const int* in_sizes, int n_in,
                              void* d_out, int out_size, void* d_ws, size_t ws_size,
                              hipStream_t stream) {
  const float* q = (const float*)d_in[0];
  const float* k = (const float*)d_in[1];
  const float* v = (const float*)d_in[2];
  const unsigned char* mask = (const unsigned char*)d_in[3];

  const long BSD = (long)BB * SS * DD;
  short* qn = (short*)d_ws;
  short* kn = qn + BSD;
  short* vtp = kn + BSD;
  unsigned short* bits = (unsigned short*)(vtp + BSD);      // 16.8 MB
  float* accG = (float*)(bits + (long)BB * SS * 256);       // 128 KB

  float* O = (float*)d_out;
  float* P = O + BSD;

  k_norm<<<dim3(2 * BB * SS / 4), dim3(256), 0, stream>>>(q, k, qn, kn);
  k_vtrans<<<dim3(SS / 64, BB), dim3(256), 0, stream>>>(v, vtp);
  k_rowsum<<<dim3(BB * SS / 64), dim3(256), 0, stream>>>(qn, kn, mask, bits, accG);
  k_attn<<<dim3(BB * SS / 64), dim3(256), 0, stream>>>(qn, kn, vtp, bits, accG, O, P);
}

// Round 8
// 281.664 us; speedup vs baseline: 1.0361x; 1.0361x over previous
//
#include <hip/hip_runtime.h>
#include <math.h>

#define BB 8
#define SS 4096
#define DD 64
#define NT (SS / 64)

#define NMB 32768   // maskbits blocks
#define NNB 16384   // norm blocks

typedef float  f32x4 __attribute__((ext_vector_type(4)));
typedef short  s16x4 __attribute__((ext_vector_type(4)));
typedef short  s16x8 __attribute__((ext_vector_type(8)));
typedef unsigned char u8x16 __attribute__((ext_vector_type(16)));

__device__ __forceinline__ short f2bf(float f) {
  unsigned u = __builtin_bit_cast(unsigned, f);
  u += 0x7FFFu + ((u >> 16) & 1u);      // RNE to bf16
  return (short)(u >> 16);
}

// packed f32x2 -> bf16x2 (RNE) via hardware cvt_pk (no builtin on gfx950)
__device__ __forceinline__ unsigned pk_bf16(float lo, float hi) {
  unsigned r;
  asm("v_cvt_pk_bf16_f32 %0, %1, %2" : "=v"(r) : "v"(lo), "v"(hi));
  return r;
}

// ---- merged pre-pass: [0,NMB) maskbits | [NMB,NMB+NNB) q/k norm | rest vtrans ----
__global__ __launch_bounds__(256) void k_pre(const float* __restrict__ q,
                                             const float* __restrict__ k,
                                             const float* __restrict__ v,
                                             const unsigned char* __restrict__ mask,
                                             short* __restrict__ qn,
                                             short* __restrict__ kn,
                                             short* __restrict__ vt,
                                             unsigned short* __restrict__ bits) {
  __shared__ short tile[64][65];
  int blk = blockIdx.x;
  int t = threadIdx.x;

  if (blk < NMB) {                       // ---- mask bytes -> bits (linear) ----
    long gid = (long)blk * 256 + t;
    u8x16 mv = __builtin_nontemporal_load((const u8x16*)(mask + gid * 16));
    unsigned r = 0;
#pragma unroll
    for (int i = 0; i < 16; i++) r |= (mv[i] ? 1u : 0u) << i;
    __builtin_nontemporal_store((unsigned short)r, bits + gid);
    return;
  }
  blk -= NMB;
  if (blk < NNB) {                       // ---- L2-normalize q,k rows -> bf16 ----
    const long BS = (long)BB * SS;
    long row = (long)blk * 4 + (t >> 6);
    int lane = t & 63;
    const float* src;
    short* dst;
    if (row < BS) { src = q + row * DD; dst = qn + row * DD; }
    else          { src = k + (row - BS) * DD; dst = kn + (row - BS) * DD; }
    float x = src[lane];
    float ss = x * x;
#pragma unroll
    for (int m = 32; m >= 1; m >>= 1) ss += __shfl_xor(ss, m);
    float inv = 1.0f / (sqrtf(ss) + 1e-10f);
    dst[lane] = f2bf(x * inv);
    return;
  }
  blk -= NNB;                            // ---- V -> VT[b][d][s] bf16 ----
  int b = blk >> 6;
  int s0 = (blk & 63) << 6;
  const float* V = v + ((long)b * SS + s0) * DD;
#pragma unroll
  for (int i = 0; i < 16; i++) {
    int flat = t + 256 * i;              // flat = sl*64 + d
    int sl = flat >> 6, d = flat & 63;
    tile[sl][d] = f2bf(V[flat]);
  }
  __syncthreads();
  short* VT = vt + (long)b * DD * SS + s0;
#pragma unroll
  for (int i = 0; i < 16; i++) {
    int flat = t + 256 * i;              // flat = d*64 + sl
    int d = flat >> 6, sl = flat & 63;
    VT[(long)d * SS + sl] = tile[sl][d];
  }
}

// ---------------- pass A: inv row-sums of exp(scores) (r2-identical) ----------------
__global__ __launch_bounds__(256) void k_rowsum(const short* __restrict__ qn,
                                                const short* __restrict__ kn,
                                                const unsigned short* __restrict__ bits,
                                                float* __restrict__ inv_sum) {
  __shared__ __align__(16) short Kt[2][4096];
  int b = blockIdx.x & 7;
  int q0 = (blockIdx.x >> 3) << 6;
  int wid = threadIdx.x >> 6, lane = threadIdx.x & 63;
  int l15 = lane & 15, g = lane >> 4;
  int qr = q0 + (wid << 4);

  const short* Qr = qn + ((long)(b * SS) + qr + l15) * DD;
  s16x8 qf0 = *(const s16x8*)(Qr + 8 * g);
  s16x8 qf1 = *(const s16x8*)(Qr + 32 + 8 * g);

  const short* Kb = kn + (long)b * SS * DD;
  const unsigned long long* B64 =
      (const unsigned long long*)bits + ((long)(b * SS) + qr + l15) * (SS / 64);

  int sr = lane >> 3, sc = lane & 7;
  int r0 = (wid << 4) + sr, r1 = r0 + 8;
  const short* Ksrc0 = Kb + (long)r0 * DD + sc * 8;
  const short* Ksrc1 = Kb + (long)r1 * DD + sc * 8;
  int kd0 = r0 * DD + ((sc ^ sr) << 3);
  int kd1 = r1 * DD + ((sc ^ sr) << 3);
  int swk = l15 & 7;

  s16x8 kst0 = *(const s16x8*)Ksrc0;
  s16x8 kst1 = *(const s16x8*)Ksrc1;
  *(s16x8*)&Kt[0][kd0] = kst0;
  *(s16x8*)&Kt[0][kd1] = kst1;
  __syncthreads();

  float acc = 0.f;
  int cur = 0;
  for (int t = 0; t < NT; ++t) {
    if (t + 1 < NT) {
      long koff = (long)(t + 1) * 64 * DD;
      kst0 = *(const s16x8*)(Ksrc0 + koff);
      kst1 = *(const s16x8*)(Ksrc1 + koff);
    }
    unsigned long long w64 = B64[t];
    const short* Kc = &Kt[cur][0];
#pragma unroll
    for (int tt = 0; tt < 4; ++tt) {
      const short* krow = Kc + ((tt << 4) + l15) * DD;
      s16x8 a0 = *(const s16x8*)(krow + ((g ^ swk) << 3));
      s16x8 a1 = *(const s16x8*)(krow + (((4 + g) ^ swk) << 3));
      f32x4 c = {0.f, 0.f, 0.f, 0.f};
      c = __builtin_amdgcn_mfma_f32_16x16x32_bf16(a0, qf0, c, 0, 0, 0);
      c = __builtin_amdgcn_mfma_f32_16x16x32_bf16(a1, qf1, c, 0, 0, 0);
#pragma unroll
      for (int r = 0; r < 4; ++r) {
        unsigned bit = (unsigned)(w64 >> ((tt << 4) + (g << 2) + r)) & 1u;
        acc += bit ? 0.f : __expf(c[r]);
      }
    }
    if (t + 1 < NT) {
      short* Kd = &Kt[cur ^ 1][0];
      *(s16x8*)(Kd + kd0) = kst0;
      *(s16x8*)(Kd + kd1) = kst1;
    }
    __syncthreads();
    cur ^= 1;
  }
  acc += __shfl_xor(acc, 16);
  acc += __shfl_xor(acc, 32);
  if (lane < 16) inv_sum[(long)b * SS + qr + l15] = 1.0f / acc;
}

// ------- pass B: recompute scores, write P, accumulate O -------
// In-loop barrier = lgkmcnt(0)+s_barrier ONLY (no vmcnt drain): P nontemporal
// stores pipeline across k-steps; compiler's dep-tracked vmcnt(N) before the
// staging ds_write orders the staging loads without draining younger stores.
__global__ __launch_bounds__(256) void k_attn(const short* __restrict__ qn,
                                              const short* __restrict__ kn,
                                              const short* __restrict__ vt,
                                              const unsigned short* __restrict__ bits,
                                              const float* __restrict__ inv_sum,
                                              float* __restrict__ O,
                                              float* __restrict__ P) {
  __shared__ __align__(16) short Kt[2][4096];
  __shared__ __align__(16) short Vt[2][4096];
  int b = blockIdx.x & 7;
  int q0 = (blockIdx.x >> 3) << 6;
  int wid = threadIdx.x >> 6, lane = threadIdx.x & 63;
  int l15 = lane & 15, g = lane >> 4;
  int qr = q0 + (wid << 4);

  const short* Qr = qn + ((long)(b * SS) + qr + l15) * DD;
  s16x8 qf0 = *(const s16x8*)(Qr + 8 * g);
  s16x8 qf1 = *(const s16x8*)(Qr + 32 + 8 * g);

  const short* Kb = kn + (long)b * SS * DD;
  const short* Vb = vt + (long)b * DD * SS;
  const unsigned long long* B64 =
      (const unsigned long long*)bits + ((long)(b * SS) + qr + l15) * (SS / 64);
  float inv = inv_sum[(long)b * SS + qr + l15];
  float linv = __logf(inv);
  float* Prow = P + ((long)(b * SS) + qr + l15) * SS;

  int sr = lane >> 3, sc = lane & 7;
  int r0 = (wid << 4) + sr, r1 = r0 + 8;
  const short* Ksrc0 = Kb + (long)r0 * DD + sc * 8;
  const short* Ksrc1 = Kb + (long)r1 * DD + sc * 8;
  const short* Vsrc0 = Vb + (long)r0 * SS + sc * 8;
  const short* Vsrc1 = Vb + (long)r1 * SS + sc * 8;
  int sd0 = r0 * DD + ((sc ^ sr) << 3);
  int sd1 = r1 * DD + ((sc ^ sr) << 3);
  int swk = l15 & 7;

  s16x8 kst0 = *(const s16x8*)Ksrc0;
  s16x8 kst1 = *(const s16x8*)Ksrc1;
  s16x8 vst0 = *(const s16x8*)Vsrc0;
  s16x8 vst1 = *(const s16x8*)Vsrc1;
  *(s16x8*)&Kt[0][sd0] = kst0;
  *(s16x8*)&Kt[0][sd1] = kst1;
  *(s16x8*)&Vt[0][sd0] = vst0;
  *(s16x8*)&Vt[0][sd1] = vst1;
  __syncthreads();

  f32x4 o0 = {0, 0, 0, 0}, o1 = {0, 0, 0, 0}, o2 = {0, 0, 0, 0}, o3 = {0, 0, 0, 0};
  int cur = 0;
  for (int t = 0; t < NT; ++t) {
    if (t + 1 < NT) {
      long koff = (long)(t + 1) * 64 * DD;
      kst0 = *(const s16x8*)(Ksrc0 + koff);
      kst1 = *(const s16x8*)(Ksrc1 + koff);
      vst0 = *(const s16x8*)(Vsrc0 + (t + 1) * 64);
      vst1 = *(const s16x8*)(Vsrc1 + (t + 1) * 64);
    }
    unsigned long long w64 = B64[t];
    const short* Kc = &Kt[cur][0];
    const short* Vc = &Vt[cur][0];

    f32x4 p[4];
#pragma unroll
    for (int tt = 0; tt < 4; ++tt) {
      const short* krow = Kc + ((tt << 4) + l15) * DD;
      s16x8 a0 = *(const s16x8*)(krow + ((g ^ swk) << 3));
      s16x8 a1 = *(const s16x8*)(krow + (((4 + g) ^ swk) << 3));
      f32x4 c = {0.f, 0.f, 0.f, 0.f};
      c = __builtin_amdgcn_mfma_f32_16x16x32_bf16(a0, qf0, c, 0, 0, 0);
      c = __builtin_amdgcn_mfma_f32_16x16x32_bf16(a1, qf1, c, 0, 0, 0);
#pragma unroll
      for (int r = 0; r < 4; ++r) {
        unsigned bit = (unsigned)(w64 >> ((tt << 4) + (g << 2) + r)) & 1u;
        p[tt][r] = bit ? 0.f : __expf(c[r] + linv);
      }
      __builtin_nontemporal_store(p[tt],
          (f32x4*)(Prow + (t << 6) + (tt << 4) + (g << 2)));
    }

    // pack P -> bf16 A-operands via v_cvt_pk_bf16_f32 (RNE)
    union { s16x8 v; unsigned u[4]; } pa0, pa1;
    pa0.u[0] = pk_bf16(p[0][0], p[0][1]);
    pa0.u[1] = pk_bf16(p[0][2], p[0][3]);
    pa0.u[2] = pk_bf16(p[1][0], p[1][1]);
    pa0.u[3] = pk_bf16(p[1][2], p[1][3]);
    pa1.u[0] = pk_bf16(p[2][0], p[2][1]);
    pa1.u[1] = pk_bf16(p[2][2], p[2][3]);
    pa1.u[2] = pk_bf16(p[3][0], p[3][1]);
    pa1.u[3] = pk_bf16(p[3][2], p[3][3]);

#pragma unroll
    for (int n = 0; n < 4; ++n) {
      const short* vrow = Vc + ((n << 4) + l15) * DD;
      int g2 = g >> 1, hh = (g & 1) << 2;
      s16x4 lo0 = *(const s16x4*)(vrow + (((g2    ) ^ swk) << 3) + hh);
      s16x4 hi0 = *(const s16x4*)(vrow + (((g2 + 2) ^ swk) << 3) + hh);
      s16x4 lo1 = *(const s16x4*)(vrow + (((g2 + 4) ^ swk) << 3) + hh);
      s16x4 hi1 = *(const s16x4*)(vrow + (((g2 + 6) ^ swk) << 3) + hh);
      s16x8 vf0 = __builtin_shufflevector(lo0, hi0, 0, 1, 2, 3, 4, 5, 6, 7);
      s16x8 vf1 = __builtin_shufflevector(lo1, hi1, 0, 1, 2, 3, 4, 5, 6, 7);
      f32x4* on = (n == 0) ? &o0 : (n == 1) ? &o1 : (n == 2) ? &o2 : &o3;
      *on = __builtin_amdgcn_mfma_f32_16x16x32_bf16(pa0.v, vf0, *on, 0, 0, 0);
      *on = __builtin_amdgcn_mfma_f32_16x16x32_bf16(pa1.v, vf1, *on, 0, 0, 0);
    }

    if (t + 1 < NT) {
      short* Kd = &Kt[cur ^ 1][0];
      short* Vd = &Vt[cur ^ 1][0];
      *(s16x8*)(Kd + sd0) = kst0;
      *(s16x8*)(Kd + sd1) = kst1;
      *(s16x8*)(Vd + sd0) = vst0;
      *(s16x8*)(Vd + sd1) = vst1;
    }
    // LDS-only barrier: drain ds ops, NOT the outstanding P stores (T4)
    asm volatile("s_waitcnt lgkmcnt(0)" ::: "memory");
    __builtin_amdgcn_sched_barrier(0);
    __builtin_amdgcn_s_barrier();
    cur ^= 1;
  }

  float* Ob = O + ((long)(b * SS) + qr) * DD;
#pragma unroll
  for (int r = 0; r < 4; ++r) {
    int row = (g << 2) + r;
    Ob[row * DD +  0 + l15] = o0[r];
    Ob[row * DD + 16 + l15] = o1[r];
    Ob[row * DD + 32 + l15] = o2[r];
    Ob[row * DD + 48 + l15] = o3[r];
  }
}

extern "C" void kernel_launch(void* const* d_in, const int* in_sizes, int n_in,
                              void* d_out, int out_size, void* d_ws, size_t ws_size,
                              hipStream_t stream) {
  const float* q = (const float*)d_in[0];
  const float* k = (const float*)d_in[1];
  const float* v = (const float*)d_in[2];
  const unsigned char* mask = (const unsigned char*)d_in[3];

  const long BSD = (long)BB * SS * DD;
  short* qn = (short*)d_ws;
  short* kn = qn + BSD;
  short* vtp = kn + BSD;
  unsigned short* bits = (unsigned short*)(vtp + BSD);      // 16.8 MB
  float* inv_sum = (float*)(bits + (long)BB * SS * 256);    // 128 KB

  float* O = (float*)d_out;
  float* P = O + BSD;

  k_pre<<<dim3(NMB + NNB + SS / 64 * BB), dim3(256), 0, stream>>>(
      q, k, v, mask, qn, kn, vtp, bits);
  k_rowsum<<<dim3(BB * SS / 64), dim3(256), 0, stream>>>(qn, kn, bits, inv_sum);
  k_attn<<<dim3(BB * SS / 64), dim3(256), 0, stream>>>(qn, kn, vtp, bits, inv_sum, O, P);
}

// Round 9
// 257.074 us; speedup vs baseline: 1.1352x; 1.0957x over previous
//
#include <hip/hip_runtime.h>
#include <math.h>

#define BB 8
#define SS 4096
#define DD 64
#define NT (SS / 64)

typedef float  f32x4 __attribute__((ext_vector_type(4)));
typedef short  s16x4 __attribute__((ext_vector_type(4)));
typedef short  s16x8 __attribute__((ext_vector_type(8)));
typedef unsigned char u8x16 __attribute__((ext_vector_type(16)));

__device__ __forceinline__ short f2bf(float f) {
  unsigned u = __builtin_bit_cast(unsigned, f);
  u += 0x7FFFu + ((u >> 16) & 1u);
  return (short)(u >> 16);
}

// ---------------- kernel 1: L2-normalize q,k rows -> bf16 ----------------
__global__ __launch_bounds__(256) void k_norm(const float* __restrict__ q,
                                              const float* __restrict__ k,
                                              short* __restrict__ qn,
                                              short* __restrict__ kn) {
  const long BS = (long)BB * SS;
  long row = (long)blockIdx.x * 4 + (threadIdx.x >> 6);
  int lane = threadIdx.x & 63;
  const float* src;
  short* dst;
  if (row < BS) { src = q + row * DD; dst = qn + row * DD; }
  else          { src = k + (row - BS) * DD; dst = kn + (row - BS) * DD; }
  float x = src[lane];
  float ss = x * x;
#pragma unroll
  for (int m = 32; m >= 1; m >>= 1) ss += __shfl_xor(ss, m);
  float inv = 1.0f / (sqrtf(ss) + 1e-10f);
  dst[lane] = f2bf(x * inv);
}

// ---------------- kernel 2: V -> VT[b][d][s] bf16 ----------------
__global__ __launch_bounds__(256) void k_vtrans(const float* __restrict__ v,
                                                short* __restrict__ vt) {
  __shared__ short tile[64][65];
  int b = blockIdx.y;
  int s0 = blockIdx.x * 64;
  const float* V = v + ((long)b * SS + s0) * DD;
  int t = threadIdx.x;
#pragma unroll
  for (int i = 0; i < 16; i++) {
    int flat = t + 256 * i;            // flat = sl*64 + d
    int sl = flat >> 6, d = flat & 63;
    tile[sl][d] = f2bf(V[flat]);
  }
  __syncthreads();
  short* VT = vt + (long)b * DD * SS + s0;
#pragma unroll
  for (int i = 0; i < 16; i++) {
    int flat = t + 256 * i;            // flat = d*64 + sl
    int d = flat >> 6, sl = flat & 63;
    VT[(long)d * SS + sl] = tile[sl][d];
  }
}

// ---------------- kernel 3: mask bytes -> bits (16x compress) ----------------
__global__ __launch_bounds__(256) void k_maskbits(const unsigned char* __restrict__ m,
                                                  unsigned short* __restrict__ bits) {
  long gid = (long)blockIdx.x * 256 + threadIdx.x;
  u8x16 v = __builtin_nontemporal_load((const u8x16*)(m + gid * 16));
  unsigned r = 0;
#pragma unroll
  for (int i = 0; i < 16; i++) r |= (v[i] ? 1u : 0u) << i;
  __builtin_nontemporal_store((unsigned short)r, bits + gid);
}

// ---------------- pass A: inv row-sums of exp(scores) ----------------
__global__ __launch_bounds__(256) void k_rowsum(const short* __restrict__ qn,
                                                const short* __restrict__ kn,
                                                const unsigned short* __restrict__ bits,
                                                float* __restrict__ inv_sum) {
  __shared__ __align__(16) short Kt[2][4096];
  int b = blockIdx.x & 7;
  int q0 = (blockIdx.x >> 3) << 6;
  int wid = threadIdx.x >> 6, lane = threadIdx.x & 63;
  int l15 = lane & 15, g = lane >> 4;
  int qr = q0 + (wid << 4);

  const short* Qr = qn + ((long)(b * SS) + qr + l15) * DD;
  s16x8 qf0 = *(const s16x8*)(Qr + 8 * g);
  s16x8 qf1 = *(const s16x8*)(Qr + 32 + 8 * g);

  const short* Kb = kn + (long)b * SS * DD;
  const unsigned long long* B64 =
      (const unsigned long long*)bits + ((long)(b * SS) + qr + l15) * (SS / 64);

  int sr = lane >> 3, sc = lane & 7;
  int r0 = (wid << 4) + sr, r1 = r0 + 8;
  const short* Ksrc0 = Kb + (long)r0 * DD + sc * 8;
  const short* Ksrc1 = Kb + (long)r1 * DD + sc * 8;
  int kd0 = r0 * DD + ((sc ^ sr) << 3);
  int kd1 = r1 * DD + ((sc ^ sr) << 3);
  int swk = l15 & 7;

  s16x8 kst0 = *(const s16x8*)Ksrc0;
  s16x8 kst1 = *(const s16x8*)Ksrc1;
  *(s16x8*)&Kt[0][kd0] = kst0;
  *(s16x8*)&Kt[0][kd1] = kst1;
  __syncthreads();

  float acc = 0.f;
  int cur = 0;
  for (int t = 0; t < NT; ++t) {
    if (t + 1 < NT) {
      long koff = (long)(t + 1) * 64 * DD;
      kst0 = *(const s16x8*)(Ksrc0 + koff);
      kst1 = *(const s16x8*)(Ksrc1 + koff);
    }
    unsigned long long w64 = B64[t];
    const short* Kc = &Kt[cur][0];
#pragma unroll
    for (int tt = 0; tt < 4; ++tt) {
      const short* krow = Kc + ((tt << 4) + l15) * DD;
      s16x8 a0 = *(const s16x8*)(krow + ((g ^ swk) << 3));
      s16x8 a1 = *(const s16x8*)(krow + (((4 + g) ^ swk) << 3));
      f32x4 c = {0.f, 0.f, 0.f, 0.f};
      c = __builtin_amdgcn_mfma_f32_16x16x32_bf16(a0, qf0, c, 0, 0, 0);
      c = __builtin_amdgcn_mfma_f32_16x16x32_bf16(a1, qf1, c, 0, 0, 0);
#pragma unroll
      for (int r = 0; r < 4; ++r) {
        unsigned bit = (unsigned)(w64 >> ((tt << 4) + (g << 2) + r)) & 1u;
        acc += bit ? 0.f : __expf(c[r]);
      }
    }
    if (t + 1 < NT) {
      short* Kd = &Kt[cur ^ 1][0];
      *(s16x8*)(Kd + kd0) = kst0;
      *(s16x8*)(Kd + kd1) = kst1;
    }
    __syncthreads();
    cur ^= 1;
  }
  acc += __shfl_xor(acc, 16);
  acc += __shfl_xor(acc, 32);
  if (lane < 16) inv_sum[(long)b * SS + qr + l15] = 1.0f / acc;
}

// ---------------- pass B: recompute scores, write P, accumulate O ----------------
// Single change vs the 252.7-us baseline: the in-loop barrier does NOT drain
// vmcnt (T4). ds ops are ordered by lgkmcnt(0)+s_barrier; sched_barrier(0x7F)
// blocks only DS ops from crossing, leaving VALU/MFMA/VMEM free to schedule.
__global__ __launch_bounds__(256) void k_attn(const short* __restrict__ qn,
                                              const short* __restrict__ kn,
                                              const short* __restrict__ vt,
                                              const unsigned short* __restrict__ bits,
                                              const float* __restrict__ inv_sum,
                                              float* __restrict__ O,
                                              float* __restrict__ P) {
  __shared__ __align__(16) short Kt[2][4096];
  __shared__ __align__(16) short Vt[2][4096];
  int b = blockIdx.x & 7;
  int q0 = (blockIdx.x >> 3) << 6;
  int wid = threadIdx.x >> 6, lane = threadIdx.x & 63;
  int l15 = lane & 15, g = lane >> 4;
  int qr = q0 + (wid << 4);

  const short* Qr = qn + ((long)(b * SS) + qr + l15) * DD;
  s16x8 qf0 = *(const s16x8*)(Qr + 8 * g);
  s16x8 qf1 = *(const s16x8*)(Qr + 32 + 8 * g);

  const short* Kb = kn + (long)b * SS * DD;
  const short* Vb = vt + (long)b * DD * SS;
  const unsigned long long* B64 =
      (const unsigned long long*)bits + ((long)(b * SS) + qr + l15) * (SS / 64);
  float inv = inv_sum[(long)b * SS + qr + l15];
  float linv = __logf(inv);
  float* Prow = P + ((long)(b * SS) + qr + l15) * SS;

  int sr = lane >> 3, sc = lane & 7;
  int r0 = (wid << 4) + sr, r1 = r0 + 8;
  const short* Ksrc0 = Kb + (long)r0 * DD + sc * 8;
  const short* Ksrc1 = Kb + (long)r1 * DD + sc * 8;
  const short* Vsrc0 = Vb + (long)r0 * SS + sc * 8;
  const short* Vsrc1 = Vb + (long)r1 * SS + sc * 8;
  int sd0 = r0 * DD + ((sc ^ sr) << 3);
  int sd1 = r1 * DD + ((sc ^ sr) << 3);
  int swk = l15 & 7;

  s16x8 kst0 = *(const s16x8*)Ksrc0;
  s16x8 kst1 = *(const s16x8*)Ksrc1;
  s16x8 vst0 = *(const s16x8*)Vsrc0;
  s16x8 vst1 = *(const s16x8*)Vsrc1;
  *(s16x8*)&Kt[0][sd0] = kst0;
  *(s16x8*)&Kt[0][sd1] = kst1;
  *(s16x8*)&Vt[0][sd0] = vst0;
  *(s16x8*)&Vt[0][sd1] = vst1;
  __syncthreads();

  f32x4 o0 = {0, 0, 0, 0}, o1 = {0, 0, 0, 0}, o2 = {0, 0, 0, 0}, o3 = {0, 0, 0, 0};
  int cur = 0;
  for (int t = 0; t < NT; ++t) {
    if (t + 1 < NT) {
      long koff = (long)(t + 1) * 64 * DD;
      kst0 = *(const s16x8*)(Ksrc0 + koff);
      kst1 = *(const s16x8*)(Ksrc1 + koff);
      vst0 = *(const s16x8*)(Vsrc0 + (t + 1) * 64);
      vst1 = *(const s16x8*)(Vsrc1 + (t + 1) * 64);
    }
    unsigned long long w64 = B64[t];
    const short* Kc = &Kt[cur][0];
    const short* Vc = &Vt[cur][0];

    f32x4 p[4];
#pragma unroll
    for (int tt = 0; tt < 4; ++tt) {
      const short* krow = Kc + ((tt << 4) + l15) * DD;
      s16x8 a0 = *(const s16x8*)(krow + ((g ^ swk) << 3));
      s16x8 a1 = *(const s16x8*)(krow + (((4 + g) ^ swk) << 3));
      f32x4 c = {0.f, 0.f, 0.f, 0.f};
      c = __builtin_amdgcn_mfma_f32_16x16x32_bf16(a0, qf0, c, 0, 0, 0);
      c = __builtin_amdgcn_mfma_f32_16x16x32_bf16(a1, qf1, c, 0, 0, 0);
#pragma unroll
      for (int r = 0; r < 4; ++r) {
        unsigned bit = (unsigned)(w64 >> ((tt << 4) + (g << 2) + r)) & 1u;
        p[tt][r] = bit ? 0.f : __expf(c[r] + linv);
      }
      __builtin_nontemporal_store(p[tt],
          (f32x4*)(Prow + (t << 6) + (tt << 4) + (g << 2)));
    }

    s16x8 pa0, pa1;
#pragma unroll
    for (int j = 0; j < 4; ++j) {
      pa0[j] = f2bf(p[0][j]); pa0[4 + j] = f2bf(p[1][j]);
      pa1[j] = f2bf(p[2][j]); pa1[4 + j] = f2bf(p[3][j]);
    }

#pragma unroll
    for (int n = 0; n < 4; ++n) {
      const short* vrow = Vc + ((n << 4) + l15) * DD;
      int g2 = g >> 1, hh = (g & 1) << 2;
      s16x4 lo0 = *(const s16x4*)(vrow + (((g2    ) ^ swk) << 3) + hh);
      s16x4 hi0 = *(const s16x4*)(vrow + (((g2 + 2) ^ swk) << 3) + hh);
      s16x4 lo1 = *(const s16x4*)(vrow + (((g2 + 4) ^ swk) << 3) + hh);
      s16x4 hi1 = *(const s16x4*)(vrow + (((g2 + 6) ^ swk) << 3) + hh);
      s16x8 vf0 = __builtin_shufflevector(lo0, hi0, 0, 1, 2, 3, 4, 5, 6, 7);
      s16x8 vf1 = __builtin_shufflevector(lo1, hi1, 0, 1, 2, 3, 4, 5, 6, 7);
      f32x4* on = (n == 0) ? &o0 : (n == 1) ? &o1 : (n == 2) ? &o2 : &o3;
      *on = __builtin_amdgcn_mfma_f32_16x16x32_bf16(pa0, vf0, *on, 0, 0, 0);
      *on = __builtin_amdgcn_mfma_f32_16x16x32_bf16(pa1, vf1, *on, 0, 0, 0);
    }

    if (t + 1 < NT) {
      short* Kd = &Kt[cur ^ 1][0];
      short* Vd = &Vt[cur ^ 1][0];
      *(s16x8*)(Kd + sd0) = kst0;
      *(s16x8*)(Kd + sd1) = kst1;
      *(s16x8*)(Vd + sd0) = vst0;
      *(s16x8*)(Vd + sd1) = vst1;
    }
    // LDS-only barrier: drain ds ops, NOT the outstanding P stores (T4).
    asm volatile("s_waitcnt lgkmcnt(0)" ::: "memory");
    __builtin_amdgcn_s_barrier();
    __builtin_amdgcn_sched_barrier(0x7F);   // only DS ops may not cross
    cur ^= 1;
  }

  float* Ob = O + ((long)(b * SS) + qr) * DD;
#pragma unroll
  for (int r = 0; r < 4; ++r) {
    int row = (g << 2) + r;
    Ob[row * DD +  0 + l15] = o0[r];
    Ob[row * DD + 16 + l15] = o1[r];
    Ob[row * DD + 32 + l15] = o2[r];
    Ob[row * DD + 48 + l15] = o3[r];
  }
}

extern "C" void kernel_launch(void* const* d_in, const int* in_sizes, int n_in,
                              void* d_out, int out_size, void* d_ws, size_t ws_size,
                              hipStream_t stream) {
  const float* q = (const float*)d_in[0];
  const float* k = (const float*)d_in[1];
  const float* v = (const float*)d_in[2];
  const unsigned char* mask = (const unsigned char*)d_in[3];

  const long BSD = (long)BB * SS * DD;
  short* qn = (short*)d_ws;
  short* kn = qn + BSD;
  short* vtp = kn + BSD;
  unsigned short* bits = (unsigned short*)(vtp + BSD);
  float* inv_sum = (float*)(bits + (long)BB * SS * (SS / 16));

  float* O = (float*)d_out;
  float* P = O + BSD;

  k_norm<<<dim3(2 * BB * SS / 4), dim3(256), 0, stream>>>(q, k, qn, kn);
  k_vtrans<<<dim3(SS / 64, BB), dim3(256), 0, stream>>>(v, vtp);
  k_maskbits<<<dim3((int)((long)BB * SS * SS / 16 / 256)), dim3(256), 0, stream>>>(mask, bits);
  k_rowsum<<<dim3(BB * SS / 64), dim3(256), 0, stream>>>(qn, kn, bits, inv_sum);
  k_attn<<<dim3(BB * SS / 64), dim3(256), 0, stream>>>(qn, kn, vtp, bits, inv_sum, O, P);
}